// Round 2
// baseline (331.578 us; speedup 1.0000x reference)
//
#include <hip/hip_runtime.h>
#include <hip/hip_bf16.h>
#include <math.h>

#define N_NODES   50000
#define N_EDGES   1600000
#define IN_F      128
#define D_ATT     64
#define N_HEADS   8
#define D_HEAD    8
#define RSQRT8    0.35355339059327373f
#define EPS_SM    1e-16f
#define NEH       (N_EDGES * N_HEADS)      // 12.8M (edge,head)

__device__ inline unsigned short f2bf(float v) {
    __hip_bfloat16 b = __float2bfloat16(v);
    return *(unsigned short*)&b;
}
__device__ inline float bflo(unsigned u) { return __uint_as_float(u << 16); }
__device__ inline float bfhi(unsigned u) { return __uint_as_float(u & 0xffff0000u); }

// ---------------------------------------------------------------------------
// K1: fused q/k/v projection, LDS-tiled SGEMM (64-node tile / block).
// Restructured vs R0: ALL THREE W tiles staged up-front (Ws[3], 96 KB) plus
// the X tile (32 KB) = 128 KB LDS, one __syncthreads, and a single k-loop
// that reads each X fragment ONCE and feeds all three accumulators.
// LDS-pipe instr count per wave drops 6x128 -> 4x128 ds_read_b128 (the
// kernel is LDS-throughput-bound; VALU is ~16 us floor at f32 peak).
// Occupancy 2 blk/CU -> 1 blk/CU, acceptable: pipe-bound not latency-bound.
// FMA order per (mm,i,j) over kk is IDENTICAL to the previous kernel ->
// bit-identical results.
// Also zeroes the segment-sum table s (stream ordering guarantees s is zero
// before K2 starts).
// q/k stored as bf16 rows [n*64 + j] (j = h*8+d) -> 128 B/node.
// v written f32 transposed to d_out[n*64 + d*8 + h].
// ---------------------------------------------------------------------------
__global__ __launch_bounds__(256) void k_proj(
        const float* __restrict__ x,
        const float* __restrict__ Wq, const float* __restrict__ bq,
        const float* __restrict__ Wk, const float* __restrict__ bk,
        const float* __restrict__ Wv, const float* __restrict__ bv,
        unsigned short* __restrict__ qp, unsigned short* __restrict__ kp,
        float* __restrict__ vout, float* __restrict__ s) {
    __shared__ float Xs[128][64];        // 32 KB   [k][node]
    __shared__ float Ws[3][128][64];     // 96 KB   [mat][k][out]
    const int tid = threadIdx.x;
    const int n0  = blockIdx.x * 64;
    const int ln  = tid & 63;
    const int kb  = tid >> 6;

    // ---- zero segment-sum table (grid-stride; 400K elements) ----
    {
        int nthr = gridDim.x * 256;
        for (int i = blockIdx.x * 256 + tid; i < N_NODES * N_HEADS; i += nthr)
            s[i] = 0.0f;
    }

    {   // stage X tile (transposed)
        int n = n0 + ln;
        if (n < N_NODES) {
            const float4* xr = (const float4*)(x + (size_t)n * IN_F + kb * 32);
#pragma unroll
            for (int i = 0; i < 8; ++i) {
                float4 v = xr[i];
                int k = kb * 32 + i * 4;
                Xs[k + 0][ln] = v.x; Xs[k + 1][ln] = v.y;
                Xs[k + 2][ln] = v.z; Xs[k + 3][ln] = v.w;
            }
        } else {
#pragma unroll
            for (int i = 0; i < 8; ++i) {
                int k = kb * 32 + i * 4;
                Xs[k + 0][ln] = 0.f; Xs[k + 1][ln] = 0.f;
                Xs[k + 2][ln] = 0.f; Xs[k + 3][ln] = 0.f;
            }
        }
    }

    {   // stage all three W tiles (transposed)
        const float* Wlist[3] = {Wq, Wk, Wv};
#pragma unroll
        for (int mm = 0; mm < 3; ++mm) {
            const float4* wr = (const float4*)(Wlist[mm] + (size_t)ln * IN_F + kb * 32);
#pragma unroll
            for (int i = 0; i < 8; ++i) {
                float4 v = wr[i];
                int k = kb * 32 + i * 4;
                Ws[mm][k + 0][ln] = v.x; Ws[mm][k + 1][ln] = v.y;
                Ws[mm][k + 2][ln] = v.z; Ws[mm][k + 3][ln] = v.w;
            }
        }
    }
    __syncthreads();

    const int tx = tid & 15;        // node group
    const int ty = tid >> 4;        // feature group

    float acc[3][4][4] = {};
#pragma unroll 2
    for (int kk = 0; kk < 128; ++kk) {
        float4 a = *(const float4*)&Xs[kk][tx * 4];
        float xr[4] = {a.x, a.y, a.z, a.w};
#pragma unroll
        for (int mm = 0; mm < 3; ++mm) {
            float4 b = *(const float4*)&Ws[mm][kk][ty * 4];
            float wr[4] = {b.x, b.y, b.z, b.w};
#pragma unroll
            for (int i = 0; i < 4; ++i)
#pragma unroll
                for (int j = 0; j < 4; ++j)
                    acc[mm][i][j] += xr[i] * wr[j];
        }
    }

    const float* blist[3] = {bq, bk, bv};
#pragma unroll
    for (int mm = 0; mm < 3; ++mm) {
        float bj[4];
#pragma unroll
        for (int j = 0; j < 4; ++j) bj[j] = blist[mm][ty * 4 + j];

#pragma unroll
        for (int i = 0; i < 4; ++i) {
            int nn = n0 + tx * 4 + i;
            if (nn >= N_NODES) continue;
            if (mm < 2) {
                unsigned short* dstp = (mm == 0 ? qp : kp) + (size_t)nn * 64 + ty * 4;
                ushort4 o;
                o.x = f2bf(acc[mm][i][0] + bj[0]);
                o.y = f2bf(acc[mm][i][1] + bj[1]);
                o.z = f2bf(acc[mm][i][2] + bj[2]);
                o.w = f2bf(acc[mm][i][3] + bj[3]);
                *(ushort4*)dstp = o;
            } else {
#pragma unroll
                for (int j = 0; j < 4; ++j) {
                    int jj = ty * 4 + j;
                    vout[(size_t)nn * 64 + (jj & 7) * 8 + (jj >> 3)] =
                        acc[mm][i][j] + bj[j];
                }
            }
        }
    }
}

// ---------------------------------------------------------------------------
// K2: prods + exp + segment-sum. 8 threads/edge (one per head); each lane
// reads a contiguous 16 B bf16 q fragment + 16 B k fragment (an edge's 8
// lanes cover its two 128 B rows exactly -> line-minimal gather).
// prods store is NONTEMPORAL: it is a pure 51.2 MB stream, never re-read
// through L2 before eviction -- keeping it out of L2 preserves capacity for
// the q/k gather working set (25.6 MB vs 32 MB aggregate L2).
// No max-subtraction: |logit| <~ 1 (verified absmax 2e-3 in R2/R3).
// ---------------------------------------------------------------------------
__global__ void k_prods_exp(const int* __restrict__ e0, const int* __restrict__ e1,
                            const float* __restrict__ ea,
                            const unsigned short* __restrict__ qp,
                            const unsigned short* __restrict__ kp,
                            float* __restrict__ prods_out,
                            float* __restrict__ s) {
    int t = blockIdx.x * blockDim.x + threadIdx.x;
    if (t >= NEH) return;
    int e = t >> 3, h = t & 7;
    int src = e0[e];
    int dst = e1[e];
    float w = ea[e] * RSQRT8;
    uint4 qv = *(const uint4*)(qp + (size_t)src * 64 + h * 8);
    uint4 kv = *(const uint4*)(kp + (size_t)dst * 64 + h * 8);
    float dot = bflo(qv.x) * bflo(kv.x) + bfhi(qv.x) * bfhi(kv.x)
              + bflo(qv.y) * bflo(kv.y) + bfhi(qv.y) * bfhi(kv.y)
              + bflo(qv.z) * bflo(kv.z) + bfhi(qv.z) * bfhi(kv.z)
              + bflo(qv.w) * bflo(kv.w) + bfhi(qv.w) * bfhi(kv.w);
    float p = dot * w;
    __builtin_nontemporal_store(p, &prods_out[t]);   // coalesced, streaming
    atomicAdd(&s[(size_t)dst * 8 + h], __expf(p));
}

// ---------------------------------------------------------------------------
// K3: att = exp(prods) / (s[dst,h] + eps).  prods read and att store are
// nontemporal streams; only s (1.6 MB, hot) and e1 stay cached.
// ---------------------------------------------------------------------------
__global__ void k_norm(const int* __restrict__ e1,
                       const float* __restrict__ prods,
                       float* __restrict__ att,
                       const float* __restrict__ s) {
    int t = blockIdx.x * blockDim.x + threadIdx.x;
    if (t >= NEH) return;
    int e = t >> 3, h = t & 7;
    int dst = e1[e];
    float pv = __builtin_nontemporal_load(&prods[t]);
    float a = __expf(pv) / (s[(size_t)dst * 8 + h] + EPS_SM);
    __builtin_nontemporal_store(a, &att[t]);
}

extern "C" void kernel_launch(void* const* d_in, const int* in_sizes, int n_in,
                              void* d_out, int out_size, void* d_ws, size_t ws_size,
                              hipStream_t stream) {
    const float* x  = (const float*)d_in[0];
    const float* Wq = (const float*)d_in[1];
    const float* bq = (const float*)d_in[2];
    const float* Wk = (const float*)d_in[3];
    const float* bk = (const float*)d_in[4];
    const float* Wv = (const float*)d_in[5];
    const float* bv = (const float*)d_in[6];
    const float* ea = (const float*)d_in[7];
    const int*   edge = (const int*)d_in[8];
    const int* e0 = edge;
    const int* e1 = edge + N_EDGES;

    float* out   = (float*)d_out;
    float* att   = out;                                  // (E, 8)
    float* vout  = att + (size_t)NEH;                    // (N, 8, 8)
    float* prods = vout + (size_t)N_NODES * D_ATT;       // (E, 8)

    unsigned short* qp = (unsigned short*)d_ws;          // (N, 64) bf16
    unsigned short* kp = qp + (size_t)N_NODES * D_ATT;   // (N, 64) bf16
    float* ssum = (float*)(kp + (size_t)N_NODES * D_ATT);// (N, 8) f32

    const int B = 256;
    int nTiles = (N_NODES + 63) / 64;
    k_proj<<<nTiles, 256, 0, stream>>>(x, Wq, bq, Wk, bk, Wv, bv,
                                       qp, kp, vout, ssum);

    int nEH = NEH;
    k_prods_exp<<<(nEH + B - 1) / B, B, 0, stream>>>(e0, e1, ea, qp, kp,
                                                     prods, ssum);

    k_norm<<<(nEH + B - 1) / B, B, 0, stream>>>(e1, prods, att, ssum);
}

// Round 4
// 300.645 us; speedup vs baseline: 1.1029x; 1.1029x over previous
//
#include <hip/hip_runtime.h>
#include <hip/hip_bf16.h>
#include <math.h>

#define N_NODES   50000
#define N_EDGES   1600000
#define IN_F      128
#define D_ATT     64
#define N_HEADS   8
#define D_HEAD    8
#define RSQRT8    0.35355339059327373f
#define EPS_SM    1e-16f
#define NEH       (N_EDGES * N_HEADS)      // 12.8M (edge,head)

// native clang vector: required by __builtin_nontemporal_load/store
typedef float f32x4 __attribute__((ext_vector_type(4)));

__device__ inline unsigned short f2bf(float v) {
    __hip_bfloat16 b = __float2bfloat16(v);
    return *(unsigned short*)&b;
}
__device__ inline float bflo(unsigned u) { return __uint_as_float(u << 16); }
__device__ inline float bfhi(unsigned u) { return __uint_as_float(u & 0xffff0000u); }

// ---------------------------------------------------------------------------
// K1: fused q/k/v projection, LDS-tiled SGEMM (64-node tile / block).
// PROVEN R0 STRUCTURE: 64 KB LDS -> 2 blocks/CU (occupancy carries the
// staging latency; the 128 KB single-sync variant regressed 27 us in R2).
// Also zeroes the segment-sum table s (stream ordering guarantees s is zero
// before K2 starts).
// q/k stored as bf16 rows [n*64 + j] (j = h*8+d) -> 128 B/node.
// v written f32 transposed to d_out[n*64 + d*8 + h].
// ---------------------------------------------------------------------------
__global__ __launch_bounds__(256) void k_proj(
        const float* __restrict__ x,
        const float* __restrict__ Wq, const float* __restrict__ bq,
        const float* __restrict__ Wk, const float* __restrict__ bk,
        const float* __restrict__ Wv, const float* __restrict__ bv,
        unsigned short* __restrict__ qp, unsigned short* __restrict__ kp,
        float* __restrict__ vout, float* __restrict__ s) {
    __shared__ float Xs[128][64];   // 32 KB
    __shared__ float Ws[128][64];   // 32 KB
    const int tid = threadIdx.x;
    const int n0  = blockIdx.x * 64;
    const int ln  = tid & 63;
    const int kb  = tid >> 6;

    // ---- zero segment-sum table (grid-stride; 400K elements) ----
    {
        int nthr = gridDim.x * 256;
        for (int i = blockIdx.x * 256 + tid; i < N_NODES * N_HEADS; i += nthr)
            s[i] = 0.0f;
    }

    {   // stage X tile (transposed)
        int n = n0 + ln;
        if (n < N_NODES) {
            const float4* xr = (const float4*)(x + (size_t)n * IN_F + kb * 32);
#pragma unroll
            for (int i = 0; i < 8; ++i) {
                float4 v = xr[i];
                int k = kb * 32 + i * 4;
                Xs[k + 0][ln] = v.x; Xs[k + 1][ln] = v.y;
                Xs[k + 2][ln] = v.z; Xs[k + 3][ln] = v.w;
            }
        } else {
#pragma unroll
            for (int i = 0; i < 8; ++i) {
                int k = kb * 32 + i * 4;
                Xs[k + 0][ln] = 0.f; Xs[k + 1][ln] = 0.f;
                Xs[k + 2][ln] = 0.f; Xs[k + 3][ln] = 0.f;
            }
        }
    }

    const int tx = tid & 15;        // node group
    const int ty = tid >> 4;        // feature group

    const float* Wlist[3] = {Wq, Wk, Wv};
    const float* blist[3] = {bq, bk, bv};

    for (int mm = 0; mm < 3; ++mm) {
        __syncthreads();
        {   // stage W tile (transposed)
            const float4* wr = (const float4*)(Wlist[mm] + (size_t)ln * IN_F + kb * 32);
#pragma unroll
            for (int i = 0; i < 8; ++i) {
                float4 v = wr[i];
                int k = kb * 32 + i * 4;
                Ws[k + 0][ln] = v.x; Ws[k + 1][ln] = v.y;
                Ws[k + 2][ln] = v.z; Ws[k + 3][ln] = v.w;
            }
        }
        __syncthreads();

        float acc[4][4] = {};
#pragma unroll 4
        for (int kk = 0; kk < 128; ++kk) {
            float4 a = *(const float4*)&Xs[kk][tx * 4];
            float4 b = *(const float4*)&Ws[kk][ty * 4];
            float xr[4] = {a.x, a.y, a.z, a.w};
            float wr[4] = {b.x, b.y, b.z, b.w};
#pragma unroll
            for (int i = 0; i < 4; ++i)
#pragma unroll
                for (int j = 0; j < 4; ++j)
                    acc[i][j] += xr[i] * wr[j];
        }

        float bj[4];
#pragma unroll
        for (int j = 0; j < 4; ++j) bj[j] = blist[mm][ty * 4 + j];

#pragma unroll
        for (int i = 0; i < 4; ++i) {
            int nn = n0 + tx * 4 + i;
            if (nn >= N_NODES) continue;
            if (mm < 2) {
                unsigned short* dstp = (mm == 0 ? qp : kp) + (size_t)nn * 64 + ty * 4;
                ushort4 o;
                o.x = f2bf(acc[i][0] + bj[0]);
                o.y = f2bf(acc[i][1] + bj[1]);
                o.z = f2bf(acc[i][2] + bj[2]);
                o.w = f2bf(acc[i][3] + bj[3]);
                *(ushort4*)dstp = o;
            } else {
#pragma unroll
                for (int j = 0; j < 4; ++j) {
                    int jj = ty * 4 + j;
                    vout[(size_t)nn * 64 + (jj & 7) * 8 + (jj >> 3)] =
                        acc[i][j] + bj[j];
                }
            }
        }
    }
}

// ---------------------------------------------------------------------------
// K2: prods + exp + segment-sum. 8 threads/edge (one per head); each lane
// reads a contiguous 16 B bf16 q fragment + 16 B k fragment (an edge's 8
// lanes cover its two 128 B rows exactly -> line-minimal gather).
// prods store nontemporal (streaming, never re-read before eviction).
// No max-subtraction: |logit| <~ 1 (verified absmax 2e-3).
// ---------------------------------------------------------------------------
__global__ void k_prods_exp(const int* __restrict__ e0, const int* __restrict__ e1,
                            const float* __restrict__ ea,
                            const unsigned short* __restrict__ qp,
                            const unsigned short* __restrict__ kp,
                            float* __restrict__ prods_out,
                            float* __restrict__ s) {
    int t = blockIdx.x * blockDim.x + threadIdx.x;
    if (t >= NEH) return;
    int e = t >> 3, h = t & 7;
    int src = e0[e];
    int dst = e1[e];
    float w = ea[e] * RSQRT8;
    uint4 qv = *(const uint4*)(qp + (size_t)src * 64 + h * 8);
    uint4 kv = *(const uint4*)(kp + (size_t)dst * 64 + h * 8);
    float dot = bflo(qv.x) * bflo(kv.x) + bfhi(qv.x) * bfhi(kv.x)
              + bflo(qv.y) * bflo(kv.y) + bfhi(qv.y) * bfhi(kv.y)
              + bflo(qv.z) * bflo(kv.z) + bfhi(qv.z) * bfhi(kv.z)
              + bflo(qv.w) * bflo(kv.w) + bfhi(qv.w) * bfhi(kv.w);
    float p = dot * w;
    __builtin_nontemporal_store(p, &prods_out[t]);   // coalesced, streaming
    atomicAdd(&s[(size_t)dst * 8 + h], __expf(p));
}

// ---------------------------------------------------------------------------
// K3: att = exp(prods) / (s[dst,h] + eps), VECTORIZED float4 (G13).
// Thread i handles t = 4i..4i+3:  e = i>>1 (two lanes share one e1 read),
// h0 = 4*(i&1) -> the s gather is ONE aligned 16-B load from the L2-hot
// 1.6 MB table.  prods/att move as 16-B nontemporal streams (f32x4 ext
// vector: HIP_vector_type float4 is rejected by the nontemporal builtins).
// 3.2M threads instead of 12.8M.
// ---------------------------------------------------------------------------
__global__ void k_norm(const int* __restrict__ e1,
                       const float* __restrict__ prods,
                       float* __restrict__ att,
                       const float* __restrict__ s) {
    int i = blockIdx.x * blockDim.x + threadIdx.x;
    if (i >= NEH / 4) return;
    int e  = i >> 1;
    int h0 = (i & 1) * 4;
    int dst = e1[e];

    f32x4 pv = __builtin_nontemporal_load(&((const f32x4*)prods)[i]);
    f32x4 sv = *(const f32x4*)(s + (size_t)dst * 8 + h0);

    f32x4 a;
    a.x = __expf(pv.x) / (sv.x + EPS_SM);
    a.y = __expf(pv.y) / (sv.y + EPS_SM);
    a.z = __expf(pv.z) / (sv.z + EPS_SM);
    a.w = __expf(pv.w) / (sv.w + EPS_SM);
    __builtin_nontemporal_store(a, &((f32x4*)att)[i]);
}

extern "C" void kernel_launch(void* const* d_in, const int* in_sizes, int n_in,
                              void* d_out, int out_size, void* d_ws, size_t ws_size,
                              hipStream_t stream) {
    const float* x  = (const float*)d_in[0];
    const float* Wq = (const float*)d_in[1];
    const float* bq = (const float*)d_in[2];
    const float* Wk = (const float*)d_in[3];
    const float* bk = (const float*)d_in[4];
    const float* Wv = (const float*)d_in[5];
    const float* bv = (const float*)d_in[6];
    const float* ea = (const float*)d_in[7];
    const int*   edge = (const int*)d_in[8];
    const int* e0 = edge;
    const int* e1 = edge + N_EDGES;

    float* out   = (float*)d_out;
    float* att   = out;                                  // (E, 8)
    float* vout  = att + (size_t)NEH;                    // (N, 8, 8)
    float* prods = vout + (size_t)N_NODES * D_ATT;       // (E, 8)

    unsigned short* qp = (unsigned short*)d_ws;          // (N, 64) bf16
    unsigned short* kp = qp + (size_t)N_NODES * D_ATT;   // (N, 64) bf16
    float* ssum = (float*)(kp + (size_t)N_NODES * D_ATT);// (N, 8) f32

    const int B = 256;
    int nTiles = (N_NODES + 63) / 64;
    k_proj<<<nTiles, 256, 0, stream>>>(x, Wq, bq, Wk, bk, Wv, bv,
                                       qp, kp, vout, ssum);

    int nEH = NEH;
    k_prods_exp<<<(nEH + B - 1) / B, B, 0, stream>>>(e0, e1, ea, qp, kp,
                                                     prods, ssum);

    int nV = NEH / 4;
    k_norm<<<(nV + B - 1) / B, B, 0, stream>>>(e1, prods, att, ssum);
}